// Round 3
// baseline (1039.778 us; speedup 1.0000x reference)
//
#include <hip/hip_runtime.h>

// Problem constants
constexpr int B  = 64, S = 512, H = 768, WE = 4, ML = 5, D = 50, T = 21;
constexpr int NT = B * S;          // 32768 tokens
constexpr int HF = H + WE * D;     // 968 feature dim
constexpr int HP = 1024;           // padded feature dim (for clean float4 tiling)
constexpr int TPW = 2;             // tokens per wave in the logits kernel
constexpr float LOG2E = 1.4426950408889634f;
constexpr float LN2   = 0.6931471805599453f;

// ---------------------------------------------------------------------------
// Kernel 0: transpose + zero-pad W (968x21) -> Wp (21x1024): aligned float4.
// ---------------------------------------------------------------------------
__global__ void k_wprep(const float* __restrict__ W, float* __restrict__ Wp) {
  int idx = blockIdx.x * 256 + threadIdx.x;
  if (idx < T * HP) {
    int t = idx >> 10;
    int h = idx & (HP - 1);
    Wp[idx] = (h < HF) ? W[h * T + t] : 0.f;
  }
}

// ---------------------------------------------------------------------------
// Kernel 1: fused lexicon gather + weighted sum + concat + matvec + bias.
// One wave = 2 tokens. acc[2][21] = 42 regs; __launch_bounds__(256,4) caps
// VGPR at 128 so the t-loop load hoisting cannot spill (round-2 lesson:
// VGPR=256 + 49 MB scratch spill traffic).
// ---------------------------------------------------------------------------
__launch_bounds__(256, 4)
__global__ void k_logits(const float* __restrict__ seq,
                         const int*   __restrict__ ids,
                         const float* __restrict__ wts,
                         const float* __restrict__ emb,
                         const float* __restrict__ Wp,
                         const float* __restrict__ bias,
                         float* __restrict__ out) {
  __shared__ __align__(16) float lexs[4][TPW * 200];
  const int wave = threadIdx.x >> 6;
  const int lane = threadIdx.x & 63;
  const int tok0 = (blockIdx.x * 4 + wave) * TPW;

  // ---- lexicon: lex[k][w*50+d] = sum_l wts[tok,w,l] * emb[ids[tok,w,l], d]
  for (int o = lane; o < TPW * 200; o += 64) {
    int k = o / 200, r = o - k * 200;
    int w = r / 50,  d = r - w * 50;
    int base = ((tok0 + k) * WE + w) * ML;
    float a = 0.f;
#pragma unroll
    for (int l = 0; l < ML; ++l) {
      int   id = ids[base + l];
      float wt = wts[base + l];
      a += wt * emb[(long)id * D + d];
    }
    lexs[wave][o] = a;
  }
  __syncthreads();

  // ---- matvec: logits[tok][t] = sum_h feat[tok][h] * Wp[t][h]
  float acc0[T], acc1[T];
#pragma unroll
  for (int t = 0; t < T; ++t) { acc0[t] = 0.f; acc1[t] = 0.f; }

#pragma unroll
  for (int it = 0; it < 4; ++it) {
    const int h0 = it * 256 + lane * 4;
    float4 f0, f1;
    if (h0 < H) {
      f0 = *(const float4*)&seq[(long)(tok0 + 0) * H + h0];
      f1 = *(const float4*)&seq[(long)(tok0 + 1) * H + h0];
    } else if (h0 < HF) {
      f0 = *(const float4*)&lexs[wave][0 * 200 + (h0 - H)];
      f1 = *(const float4*)&lexs[wave][1 * 200 + (h0 - H)];
    } else {
      f0 = make_float4(0.f, 0.f, 0.f, 0.f);
      f1 = f0;
    }
#pragma unroll
    for (int tg = 0; tg < 3; ++tg) {
#pragma unroll
      for (int t7 = 0; t7 < 7; ++t7) {
        const int t = tg * 7 + t7;
        float4 wv = *(const float4*)&Wp[t * HP + h0];
        acc0[t] += f0.x * wv.x + f0.y * wv.y + f0.z * wv.z + f0.w * wv.w;
        acc1[t] += f1.x * wv.x + f1.y * wv.y + f1.z * wv.z + f1.w * wv.w;
      }
    }
  }

  // ---- cross-lane reduce
#pragma unroll
  for (int t = 0; t < T; ++t) {
    float v0 = acc0[t], v1 = acc1[t];
#pragma unroll
    for (int m = 32; m; m >>= 1) {
      v0 += __shfl_xor(v0, m, 64);
      v1 += __shfl_xor(v1, m, 64);
    }
    acc0[t] = v0; acc1[t] = v1;
  }

  if (lane == 0) {
#pragma unroll
    for (int t = 0; t < T; ++t) {
      out[(long)(tok0 + 0) * T + t] = acc0[t] + bias[t];
      out[(long)(tok0 + 1) * T + t] = acc1[t] + bias[t];
    }
  }
}

// ---------------------------------------------------------------------------
// Kernel 2: CRF NLL per sequence. One wave per b. lane j = lane%21 holds
// alpha[j] in log2 domain. Max-free logsumexp (shift = alpha[0]; cross-state
// spread is bounded by emission spread so exp2 args stay in ~[-12,12]).
// Emissions+mask pipelined 4 chunks (12 steps, ~1000 cy) ahead in NAMED regs.
// ---------------------------------------------------------------------------
__global__ void k_crf(const float* __restrict__ logits,
                      const int*   __restrict__ labels,
                      const int*   __restrict__ mask,
                      const float* __restrict__ start_t,
                      const float* __restrict__ end_t,
                      const float* __restrict__ trans,
                      float* __restrict__ part) {
  const int b = blockIdx.x;
  const int lane = threadIdx.x;       // block = 64 = 1 wave
  const long base = (long)b * S;
  const int j = lane % 21;
  int p = lane / 21; if (p == 3) p = 0;   // lane 63 duplicates lane 0
  const int i0 = p * 7;

  // TR[ii] = trans[i0+ii][j] * log2(e)  (base-2 domain)
  float TR[7];
#pragma unroll
  for (int ii = 0; ii < 7; ++ii) TR[ii] = trans[(i0 + ii) * T + j] * LOG2E;

  // ---- numerator (gold path), parallel over s + butterfly reduce
  float np = 0.f; int cnt = 0;
  for (int s = lane; s < S; s += 64) {
    int tg = labels[base + s];
    int mk = mask[base + s];
    cnt += mk;
    if (s == 0) {
      np += start_t[tg] + logits[base * T + tg];
    } else {
      int tp = labels[base + s - 1];
      np += mk ? (trans[tp * T + tg] + logits[(base + s) * T + tg]) : 0.f;
    }
  }
#pragma unroll
  for (int m = 32; m; m >>= 1) {
    np  += __shfl_xor(np, m, 64);
    cnt += __shfl_xor(cnt, m, 64);
  }
  int last = cnt - 1;
  int lt = labels[base + last];
  float num = np + end_t[lt];

  // ---- forward scan: chunks of 3 steps, 63 lanes load 3x21 emissions
  const int lq = lane / 21;                    // 0..3 (3 unused)
  const int lr = lane - 21 * (lq < 3 ? lq : 0);
  const int lm = lane < 2 ? lane : 2;

#define CRF_LOAD(E, M, c) do {                                   \
    int _se = 1 + 3 * (c) + lq; if (_se > S - 1) _se = S - 1;    \
    E = logits[(base + _se) * T + lr];                           \
    int _sm = 1 + 3 * (c) + lm; if (_sm > S - 1) _sm = S - 1;    \
    M = mask[base + _sm];                                        \
  } while (0)

#define CRF_STEP(E, M, c, stp) do {                              \
    const int _s = 1 + 3 * (c) + (stp);                          \
    float en = __shfl(E, (stp) * 21 + j, 64);                    \
    int   mk = __shfl(M, (stp), 64);                             \
    float sh = __shfl(A, 0, 64);                                 \
    float p0 = exp2f(__shfl(A, i0 + 0, 64) + (TR[0] - sh));      \
    float p1 = exp2f(__shfl(A, i0 + 1, 64) + (TR[1] - sh));      \
    float p2 = exp2f(__shfl(A, i0 + 2, 64) + (TR[2] - sh));      \
    float p3 = exp2f(__shfl(A, i0 + 3, 64) + (TR[3] - sh));      \
    float p4 = exp2f(__shfl(A, i0 + 4, 64) + (TR[4] - sh));      \
    float p5 = exp2f(__shfl(A, i0 + 5, 64) + (TR[5] - sh));      \
    float p6 = exp2f(__shfl(A, i0 + 6, 64) + (TR[6] - sh));      \
    float ss = ((p0 + p1) + (p2 + p3)) + ((p4 + p5) + p6);       \
    float s1 = __shfl(ss, j, 64);                                \
    float s2 = __shfl(ss, j + 21, 64);                           \
    float s3 = __shfl(ss, j + 42, 64);                           \
    float An = fmaf(en, LOG2E, sh) + __log2f((s1 + s2) + s3);    \
    A = (mk && _s < S) ? An : A;                                 \
  } while (0)

#define CRF_STEP3(E, M, c) do { CRF_STEP(E, M, c, 0); CRF_STEP(E, M, c, 1); CRF_STEP(E, M, c, 2); } while (0)

  // alpha[j] in log2 domain
  float A = (start_t[j] + logits[base * T + j]) * LOG2E;

  float E0, E1, E2, E3; int M0, M1, M2, M3;
  CRF_LOAD(E0, M0, 0); CRF_LOAD(E1, M1, 1);
  CRF_LOAD(E2, M2, 2); CRF_LOAD(E3, M3, 3);

  // 172 chunks cover steps 1..516 (guarded); 43 groups x 4 chunks
  for (int g = 0; g < 43; ++g) {
    const int c = 4 * g;
    CRF_STEP3(E0, M0, c + 0); CRF_LOAD(E0, M0, c + 4);
    CRF_STEP3(E1, M1, c + 1); CRF_LOAD(E1, M1, c + 5);
    CRF_STEP3(E2, M2, c + 2); CRF_LOAD(E2, M2, c + 6);
    CRF_STEP3(E3, M3, c + 3); CRF_LOAD(E3, M3, c + 7);
  }
#undef CRF_LOAD
#undef CRF_STEP
#undef CRF_STEP3

  // ---- logZ = logsumexp_j(alpha[j] + end[j])  (back to ln domain)
  float a_ln = A * LN2;
  float y  = (lane < T) ? a_ln + end_t[lane] : -3e38f;
  float ym = y;
#pragma unroll
  for (int m = 32; m; m >>= 1) ym = fmaxf(ym, __shfl_xor(ym, m, 64));
  float z = (lane < T) ? exp2f((y - ym) * LOG2E) : 0.f;
#pragma unroll
  for (int m = 32; m; m >>= 1) z += __shfl_xor(z, m, 64);
  float logZ = ym + LN2 * __log2f(z);

  if (lane == 0) part[b] = logZ - num;
}

// ---------------------------------------------------------------------------
// Kernel 3: loss = sum_b part[b]
// ---------------------------------------------------------------------------
__global__ void k_loss(const float* __restrict__ part, float* __restrict__ out_loss) {
  int lane = threadIdx.x;
  float v = part[lane];                  // B == 64 exactly
#pragma unroll
  for (int m = 32; m; m >>= 1) v += __shfl_xor(v, m, 64);
  if (lane == 0) out_loss[0] = v;
}

// ---------------------------------------------------------------------------
extern "C" void kernel_launch(void* const* d_in, const int* in_sizes, int n_in,
                              void* d_out, int out_size, void* d_ws, size_t ws_size,
                              hipStream_t stream) {
  const float* seq  = (const float*)d_in[0];
  const int*   ids  = (const int*)  d_in[1];
  const float* wts  = (const float*)d_in[2];
  const int*   lbl  = (const int*)  d_in[3];
  const int*   msk  = (const int*)  d_in[4];
  const float* emb  = (const float*)d_in[5];
  const float* W    = (const float*)d_in[6];
  const float* bias = (const float*)d_in[7];
  const float* st   = (const float*)d_in[8];
  const float* en   = (const float*)d_in[9];
  const float* tr   = (const float*)d_in[10];

  float* out  = (float*)d_out;           // [NT*T logits][1 loss]
  float* Wp   = (float*)d_ws;            // 21*1024 floats
  float* part = Wp + T * HP;             // 64 floats

  k_wprep <<<(T * HP + 255) / 256, 256, 0, stream>>>(W, Wp);
  k_logits<<<NT / (4 * TPW), 256, 0, stream>>>(seq, ids, wts, emb, Wp, bias, out);
  k_crf   <<<B, 64, 0, stream>>>(out, lbl, msk, st, en, tr, part);
  k_loss  <<<1, 64, 0, stream>>>(part, out + (long)NT * T);
}